// Round 9
// baseline (405.760 us; speedup 1.0000x reference)
//
#include <hip/hip_runtime.h>

// Fused CircularBoundaryBlock:
//   out = relu(LN(x + W2 @ relu(W1 @ [roll(x,1), x, roll(x,-1)] + b1) + b2))
// B=4, N=65536, H=128, fp32 I/O, bf16 MFMA internally.
//
// v10: cross the register-occupancy wall (16 waves/CU).
//   Diagnosis across v2/v4/v8/v9: waves/CU steps at total-regs {64,128,256};
//   resident weights (128 regs) pin the kernel at 224-256 total -> 8 waves/CU
//   forever. v10 streams weights from a packed, fragment-ordered bf16 buffer
//   (d_ws, 128 KB, L2-resident) with a 1-deep prefetch CHAINED across phases
//   (GEMM1 tail prefetches W2 frags; GEMM2 tail prefetches next iter's W1),
//   so total regs ~= acc 32 (AGPR) + xreg 36 + stream 16 + temps -> <=128.
//   v2's earlier streaming attempt failed via SPILL (arch starved under the
//   same cap while holding v1-era structure), not via streaming traffic.
//   Also: ps2 partials pre-reduced over the g-dimension with shfl_xor
//   (cross-wave part only goes through LDS): ps2 9.2 KB -> 2 KB.
//   LDS total 39.4 KB -> 4 blocks/CU; GRID 1024 (4 even iters, 4 resident).
// Kept from v8: LN-direct epilogue (no vs), swapped-operand MFMA, T14 stage
// split + halo prefetch, biases/gamma/beta in tiny LDS, 3 barriers/iter,
// setprio, 256 thr. Tripwire: FETCH/WRITE inflation = spill -> revert to v8.

typedef __bf16 bf16x8 __attribute__((ext_vector_type(8)));
typedef __bf16 bf16x4 __attribute__((ext_vector_type(4)));
typedef float  f32x4  __attribute__((ext_vector_type(4)));

#define H      128
#define NB     65536        // rows per batch
#define TILE   64
#define XS     136          // x LDS stride (bf16 elems)
#define HSS    136          // h LDS stride (bf16 elems)
#define NTILES 4096         // 4 * 65536 / 64
#define GRID   1024         // 4 blocks/CU resident, 4 even iters/block

#define W1P_ELEMS 49152     // 12 ks * 4 wid * 2 ct * 64 lane * 8
#define W2P_ELEMS 16384     // 4 ks * ...

// ---- prep: pack W1/W2 into per-wave MFMA fragment order (bf16) ----
// idx = ks*4096 + wid*1024 + ct*512 + lane*8 + j
// frag element j for lane (g,l) = W[(ks*32 + g*8 + j)*H + (wid*32 + ct*16 + l)]
__global__ __launch_bounds__(256)
void pack_w(const float* __restrict__ W1, const float* __restrict__ W2,
            __bf16* __restrict__ wp) {
    const int i = blockIdx.x * 256 + threadIdx.x;
    if (i >= W1P_ELEMS + W2P_ELEMS) return;
    const int isW2 = (i >= W1P_ELEMS);
    const int ib = isW2 ? i - W1P_ELEMS : i;
    const float* src = isW2 ? W2 : W1;
    const int j    = ib & 7;
    const int lane = (ib >> 3) & 63;
    const int ct   = (ib >> 9) & 1;
    const int w    = (ib >> 10) & 3;
    const int ks   = ib >> 12;
    const int row  = ks * 32 + (lane >> 4) * 8 + j;
    const int col  = w * 32 + ct * 16 + (lane & 15);
    wp[i] = (__bf16)src[row * H + col];
}

__global__ __launch_bounds__(256, 4)
void cbb_kernel(const float* __restrict__ x,
                const float* __restrict__ b1, const float* __restrict__ b2,
                const float* __restrict__ gamma, const float* __restrict__ beta,
                const __bf16* __restrict__ wp, float* __restrict__ out) {
    // xs (66*136 bf16) + hs (64*136 bf16) = 35360 B
    __shared__ __align__(16) char raw[(66 * XS + 64 * HSS) * 2];
    __bf16* xs = (__bf16*)raw;
    __bf16* hs = xs + 66 * XS;
    __shared__ __align__(16) float2 ps2[64 * 4];   // LN partials, 2 KB (g-reduced)
    __shared__ __align__(16) float s_b1[128], s_b2[128], s_gamma[128], s_beta[128];

    const int tid  = threadIdx.x;
    const int wid  = tid >> 6;
    const int lane = tid & 63;
    const int l    = lane & 15;   // MFMA n index (tile row, after swap)
    const int g    = lane >> 4;   // MFMA quad
    const int col0 = wid * 32;

    if (tid < 128) {
        s_b1[tid] = b1[tid];   s_b2[tid]   = b2[tid];
        s_gamma[tid] = gamma[tid]; s_beta[tid] = beta[tid];
    }

    // per-thread bases into the packed weight buffer
    const __bf16* w1p = wp + (wid * 1024 + lane * 8);
    const __bf16* w2p = wp + W1P_ELEMS + (wid * 1024 + lane * 8);

    // ---- T14 prefetch: full 66-row halo tile (8 float4 + tid<64 halo) ----
    float4 xreg[8];
    float4 xhalo;
    {
        const int t  = blockIdx.x;
        const int b  = t >> 10;
        const int n0 = (t & 1023) << 6;
        const size_t rowbase = (size_t)b * NB;
#pragma unroll
        for (int s = 0; s < 8; ++s) {
            const int q = tid + s * 256;            // q < 2048 -> rows 0..63
            const int r = q >> 5, c = q & 31;
            const int grow = (n0 - 1 + r + NB) & (NB - 1);
            xreg[s] = *(const float4*)(x + ((rowbase + grow) * H + c * 4));
        }
        if (tid < 64) {                              // rows 64,65
            const int q = 2048 + tid;
            const int r = q >> 5, c = q & 31;
            const int grow = (n0 - 1 + r + NB) & (NB - 1);
            xhalo = *(const float4*)(x + ((rowbase + grow) * H + c * 4));
        }
    }

    // weight stream prologue: W1 ks=0 frags in flight before the loop
    bf16x8 wc0 = *(const bf16x8*)(w1p);
    bf16x8 wc1 = *(const bf16x8*)(w1p + 512);

    for (int t = blockIdx.x; t < NTILES; t += GRID) {
        const int b  = t >> 10;
        const int n0 = (t & 1023) << 6;
        const size_t rowbase = (size_t)b * NB;

        // no loop-top barrier: prev-iter xs/hs readers ordered by B4(ps2)

        // ---- stage: consume prefetched regs -> xs (bf16) ----
#pragma unroll
        for (int s = 0; s < 8; ++s) {
            const int q = tid + s * 256;
            const int r = q >> 5, c = q & 31;
            bf16x4 v4;
            v4[0] = (__bf16)xreg[s].x; v4[1] = (__bf16)xreg[s].y;
            v4[2] = (__bf16)xreg[s].z; v4[3] = (__bf16)xreg[s].w;
            *(bf16x4*)(xs + r * XS + c * 4) = v4;
        }
        if (tid < 64) {
            const int q = 2048 + tid;
            const int r = q >> 5, c = q & 31;
            bf16x4 v4;
            v4[0] = (__bf16)xhalo.x; v4[1] = (__bf16)xhalo.y;
            v4[2] = (__bf16)xhalo.z; v4[3] = (__bf16)xhalo.w;
            *(bf16x4*)(xs + r * XS + c * 4) = v4;
        }
        __syncthreads();  // B2: xs tile visible

        // ---- issue next tile's loads; they fly under GEMM1/GEMM2/LN ----
        if (t + GRID < NTILES) {
            const int tn  = t + GRID;
            const int bn  = tn >> 10;
            const int n0n = (tn & 1023) << 6;
            const size_t rbn = (size_t)bn * NB;
#pragma unroll
            for (int s = 0; s < 8; ++s) {
                const int q = tid + s * 256;
                const int r = q >> 5, c = q & 31;
                const int grow = (n0n - 1 + r + NB) & (NB - 1);
                xreg[s] = *(const float4*)(x + ((rbn + grow) * H + c * 4));
            }
            if (tid < 64) {
                const int q = 2048 + tid;
                const int r = q >> 5, c = q & 31;
                const int grow = (n0n - 1 + r + NB) & (NB - 1);
                xhalo = *(const float4*)(x + ((rbn + grow) * H + c * 4));
            }
        }

        // ---- GEMM1 (swapped, streamed weights): acc = D[hcol quad][tilerow] ----
        f32x4 acc[4][2];
#pragma unroll
        for (int rt = 0; rt < 4; ++rt)
#pragma unroll
            for (int ct = 0; ct < 2; ++ct)
                acc[rt][ct] = (f32x4){0.f, 0.f, 0.f, 0.f};

        __builtin_amdgcn_s_setprio(1);
#pragma unroll
        for (int ks = 0; ks < 12; ++ks) {
            // prefetch next frag pair; at the tail, prefetch GEMM2 ks=0
            bf16x8 wn0, wn1;
            if (ks < 11) {
                wn0 = *(const bf16x8*)(w1p + (ks + 1) * 4096);
                wn1 = *(const bf16x8*)(w1p + (ks + 1) * 4096 + 512);
            } else {
                wn0 = *(const bf16x8*)(w2p);
                wn1 = *(const bf16x8*)(w2p + 512);
            }
            const int k  = ks * 32 + g * 8;          // k in [0,384)
            const int ro = k >> 7, kc = k & 127;
#pragma unroll
            for (int rt = 0; rt < 4; ++rt) {
                const bf16x8 a = *(const bf16x8*)(xs + (rt * 16 + l + ro) * XS + kc);
                acc[rt][0] = __builtin_amdgcn_mfma_f32_16x16x32_bf16(wc0, a, acc[rt][0], 0, 0, 0);
                acc[rt][1] = __builtin_amdgcn_mfma_f32_16x16x32_bf16(wc1, a, acc[rt][1], 0, 0, 0);
            }
            wc0 = wn0; wc1 = wn1;
        }
        __builtin_amdgcn_s_setprio(0);

        // relu + bias -> hs: lane holds cols col0+ct*16+g*4..+3 of row rt*16+l
        {
            const f32x4 b1q0 = *(const f32x4*)(s_b1 + col0 + g * 4);
            const f32x4 b1q1 = *(const f32x4*)(s_b1 + col0 + 16 + g * 4);
#pragma unroll
            for (int rt = 0; rt < 4; ++rt) {
                bf16x4 h0, h1;
#pragma unroll
                for (int i = 0; i < 4; ++i) {
                    h0[i] = (__bf16)fmaxf(acc[rt][0][i] + b1q0[i], 0.f);
                    h1[i] = (__bf16)fmaxf(acc[rt][1][i] + b1q1[i], 0.f);
                }
                *(bf16x4*)(hs + (rt * 16 + l) * HSS + col0 + g * 4)      = h0;
                *(bf16x4*)(hs + (rt * 16 + l) * HSS + col0 + 16 + g * 4) = h1;
            }
        }
        __syncthreads();  // B3: hs tile visible (w2 ks=0 frags landing meanwhile)

        // ---- GEMM2 (swapped, streamed): delta[outcol quad][tilerow] ----
        f32x4 acc2[4][2];
#pragma unroll
        for (int rt = 0; rt < 4; ++rt)
#pragma unroll
            for (int ct = 0; ct < 2; ++ct)
                acc2[rt][ct] = (f32x4){0.f, 0.f, 0.f, 0.f};

        __builtin_amdgcn_s_setprio(1);
#pragma unroll
        for (int ks = 0; ks < 4; ++ks) {
            // prefetch next; at the tail, prefetch next ITERATION's W1 ks=0
            bf16x8 wn0, wn1;
            if (ks < 3) {
                wn0 = *(const bf16x8*)(w2p + (ks + 1) * 4096);
                wn1 = *(const bf16x8*)(w2p + (ks + 1) * 4096 + 512);
            } else {
                wn0 = *(const bf16x8*)(w1p);
                wn1 = *(const bf16x8*)(w1p + 512);
            }
#pragma unroll
            for (int rt = 0; rt < 4; ++rt) {
                const bf16x8 a = *(const bf16x8*)(hs + (rt * 16 + l) * HSS + ks * 32 + g * 8);
                acc2[rt][0] = __builtin_amdgcn_mfma_f32_16x16x32_bf16(wc0, a, acc2[rt][0], 0, 0, 0);
                acc2[rt][1] = __builtin_amdgcn_mfma_f32_16x16x32_bf16(wc1, a, acc2[rt][1], 0, 0, 0);
            }
            wc0 = wn0; wc1 = wn1;
        }
        __builtin_amdgcn_s_setprio(0);

        // ---- residual: v = x + delta + b2 (vectorized b64 x re-read) ----
        {
            const f32x4 b2q0 = *(const f32x4*)(s_b2 + col0 + g * 4);
            const f32x4 b2q1 = *(const f32x4*)(s_b2 + col0 + 16 + g * 4);
#pragma unroll
            for (int rt = 0; rt < 4; ++rt) {
                const bf16x4 xv0 = *(const bf16x4*)(xs + (rt * 16 + l + 1) * XS + col0 + g * 4);
                const bf16x4 xv1 = *(const bf16x4*)(xs + (rt * 16 + l + 1) * XS + col0 + 16 + g * 4);
#pragma unroll
                for (int i = 0; i < 4; ++i) {
                    acc2[rt][0][i] += b2q0[i] + (float)xv0[i];
                    acc2[rt][1][i] += b2q1[i] + (float)xv1[i];
                }
            }
        }

        // ---- LN partials: per-lane (s,q) over 8 cols, shfl-reduce over g, ----
        // ---- then one float2/(row,wid) to 2 KB ps2                        ----
#pragma unroll
        for (int rt = 0; rt < 4; ++rt) {
            float s = 0.f, qq = 0.f;
#pragma unroll
            for (int ct = 0; ct < 2; ++ct)
#pragma unroll
                for (int i = 0; i < 4; ++i) {
                    const float v = acc2[rt][ct][i];
                    s += v; qq += v * v;
                }
            s  += __shfl_xor(s, 16);  s  += __shfl_xor(s, 32);
            qq += __shfl_xor(qq, 16); qq += __shfl_xor(qq, 32);
            if (g == 0) ps2[(rt * 16 + l) * 4 + wid] = make_float2(s, qq);
        }
        __syncthreads();  // B4: partials visible; frees xs/hs for next iter

        // ---- row stats for assigned row (= lane): 2 aligned b128 reads ----
        float mu, rv;
        {
            const f32x4* pp = (const f32x4*)(ps2 + lane * 4);  // 32 B/row
            const f32x4 e0 = pp[0], e1 = pp[1];
            const float S = e0[0] + e0[2] + e1[0] + e1[2];
            const float Q = e0[1] + e0[3] + e1[1] + e1[3];
            mu = S * (1.f / 128.f);
            const float var = Q * (1.f / 128.f) - mu * mu;
            rv = rsqrtf(var + 1e-5f);
        }

        // ---- normalize + relu in-reg, store f32x4 direct to global ----
        {
            const f32x4 gm0 = *(const f32x4*)(s_gamma + col0 + g * 4);
            const f32x4 gm1 = *(const f32x4*)(s_gamma + col0 + 16 + g * 4);
            const f32x4 bt0 = *(const f32x4*)(s_beta + col0 + g * 4);
            const f32x4 bt1 = *(const f32x4*)(s_beta + col0 + 16 + g * 4);
#pragma unroll
            for (int rt = 0; rt < 4; ++rt) {
                const float mur = __shfl(mu, (lane & 15) + rt * 16);
                const float rvr = __shfl(rv, (lane & 15) + rt * 16);
                float* op = out + (rowbase + n0 + rt * 16 + l) * H + col0;
                f32x4 o0, o1;
#pragma unroll
                for (int i = 0; i < 4; ++i) {
                    o0[i] = fmaxf((acc2[rt][0][i] - mur) * rvr * gm0[i] + bt0[i], 0.f);
                    o1[i] = fmaxf((acc2[rt][1][i] - mur) * rvr * gm1[i] + bt1[i], 0.f);
                }
                *(f32x4*)(op + g * 4)      = o0;
                *(f32x4*)(op + 16 + g * 4) = o1;
            }
        }
    }
}

extern "C" void kernel_launch(void* const* d_in, const int* in_sizes, int n_in,
                              void* d_out, int out_size, void* d_ws, size_t ws_size,
                              hipStream_t stream) {
    const float* x     = (const float*)d_in[0];
    const float* W1    = (const float*)d_in[1];
    const float* b1    = (const float*)d_in[2];
    const float* W2    = (const float*)d_in[3];
    const float* b2    = (const float*)d_in[4];
    const float* gamma = (const float*)d_in[5];
    const float* beta  = (const float*)d_in[6];
    float* out = (float*)d_out;
    __bf16* wp = (__bf16*)d_ws;   // 131072 B packed weights

    // pack weights fragment-ordered (re-done every launch: inputs may change)
    pack_w<<<256, 256, 0, stream>>>(W1, W2, wp);

    // 1024 blocks, 4 resident/CU (LDS 39.4 KB, regs <=128); 4 even iters
    cbb_kernel<<<GRID, 256, 0, stream>>>(x, b1, b2, gamma, beta, wp, out);
}

// Round 10
// 269.742 us; speedup vs baseline: 1.5043x; 1.5043x over previous
//
#include <hip/hip_runtime.h>

// Fused CircularBoundaryBlock:
//   out = relu(LN(x + W2 @ relu(W1 @ [roll(x,1), x, roll(x,-1)] + b1) + b2))
// B=4, N=65536, H=128, fp32 I/O, bf16 MFMA internally.
//
// v11 = v8 + LN deferred-normalize software pipeline.
//   v2/v4/v9/v10 proved the >8-waves/CU lever is unreachable (intrinsic live
//   set ~120 regs > the 128-total cap 16 waves needs -> spill, 4/4 attempts).
//   So optimize WITHIN the 8-wave band: v8's post-B4 region is VALU-only
//   (LN normalize + store, ~600 cyc) with nothing on the MFMA pipe. MFMA and
//   VALU pipes co-issue across/within waves (m114), so v11 defers the heavy
//   normalize+store of tile t into tile t+GRID's GEMM1 region:
//     post-B4: compute only row stats (2 b128 + ~12 VALU), keep
//     dacc/dmu/drv/dop live across the loop edge; emit deferred
//     normalize+store right after B2, interleaving with GEMM1 MFMA.
//   Legality: deferred code touches regs + s_gamma/s_beta (never clobbered)
//   + global only; dacc+xreg were already co-live in v8 (no new spill);
//   other waves can't write ps2(t+1) until B3, after our B3 arrival.
// Everything else identical to v8 (best, 98us/dispatch): W1 frags in regs,
// W2 frags in LDS, swapped-operand MFMA, LN-direct epilogue, T14 stage split
// + halo prefetch, biases/gamma/beta in tiny LDS, 3 barriers/iter, setprio,
// 256 thr, 512 blocks, 2 blocks/CU.

typedef __bf16 bf16x8 __attribute__((ext_vector_type(8)));
typedef __bf16 bf16x4 __attribute__((ext_vector_type(4)));
typedef float  f32x4  __attribute__((ext_vector_type(4)));

#define H      128
#define NB     65536        // rows per batch
#define TILE   64
#define XS     136          // x LDS stride (bf16 elems)
#define HSS    136          // h LDS stride (bf16 elems)
#define PSS    18           // ps2 stride (float2), 144 B: 16B-aligned rows
#define NTILES 4096         // 4 * 65536 / 64
#define GRID   512          // 2 blocks/CU * 256 CUs

__global__ __launch_bounds__(256, 2)
void cbb_kernel(const float* __restrict__ x, const float* __restrict__ W1,
                const float* __restrict__ b1, const float* __restrict__ W2,
                const float* __restrict__ b2, const float* __restrict__ gamma,
                const float* __restrict__ beta, float* __restrict__ out) {
    // xs (66*136 bf16) + hs (64*136 bf16) = 35360 B (no vs buffer)
    __shared__ __align__(16) char raw[(66 * XS + 64 * HSS) * 2];
    __bf16* xs = (__bf16*)raw;
    __bf16* hs = xs + 66 * XS;
    __shared__ __align__(16) __bf16 w2s[16384];    // W2 frags, 32 KB, persistent
    __shared__ __align__(16) float2 ps2[64 * PSS]; // LN partials, 9216 B
    __shared__ __align__(16) float s_b1[128], s_b2[128], s_gamma[128], s_beta[128];

    const int tid  = threadIdx.x;
    const int wid  = tid >> 6;
    const int lane = tid & 63;
    const int l    = lane & 15;   // MFMA n index (tile row, after swap)
    const int g    = lane >> 4;   // MFMA quad
    const int col0 = wid * 32;

    if (tid < 128) {
        s_b1[tid] = b1[tid];   s_b2[tid]   = b2[tid];
        s_gamma[tid] = gamma[tid]; s_beta[tid] = beta[tid];
    }

    // ---- W1 B-fragments persistent in registers (this wave's 32-col slice) ----
    bf16x8 w1f[12][2];
#pragma unroll
    for (int ks = 0; ks < 12; ++ks) {
#pragma unroll
        for (int ct = 0; ct < 2; ++ct) {
            const int cc = col0 + ct * 16 + l;
            bf16x8 f;
#pragma unroll
            for (int j = 0; j < 8; ++j)
                f[j] = (__bf16)W1[(ks * 32 + g * 8 + j) * H + cc];
            w1f[ks][ct] = f;
        }
    }

    // ---- W2 B-fragments -> LDS, fragment-ordered (once per block) ----
    // layout: w2s[w*4096 + ks*1024 + ct*512 + lane*8 + j]
    for (int idx = tid; idx < 16384; idx += 256) {
        const int j  = idx & 7;
        const int ln = (idx >> 3) & 63;
        const int ct = (idx >> 9) & 1;
        const int ks = (idx >> 10) & 3;
        const int w  = idx >> 12;
        const int row = ks * 32 + (ln >> 4) * 8 + j;
        const int col = w * 32 + ct * 16 + (ln & 15);
        w2s[idx] = (__bf16)W2[row * H + col];
    }
    const __bf16* w2w = w2s + wid * 4096;

    // ---- T14 prefetch: full 66-row halo tile (8 float4 + tid<64 halo) ----
    float4 xreg[8];
    float4 xhalo;
    {
        const int t  = blockIdx.x;
        const int b  = t >> 10;
        const int n0 = (t & 1023) << 6;
        const size_t rowbase = (size_t)b * NB;
#pragma unroll
        for (int s = 0; s < 8; ++s) {
            const int q = tid + s * 256;            // q < 2048 -> rows 0..63
            const int r = q >> 5, c = q & 31;
            const int grow = (n0 - 1 + r + NB) & (NB - 1);
            xreg[s] = *(const float4*)(x + ((rowbase + grow) * H + c * 4));
        }
        if (tid < 64) {                              // rows 64,65
            const int q = 2048 + tid;
            const int r = q >> 5, c = q & 31;
            const int grow = (n0 - 1 + r + NB) & (NB - 1);
            xhalo = *(const float4*)(x + ((rowbase + grow) * H + c * 4));
        }
    }

    // ---- deferred-LN pipeline state (carried across iterations) ----
    f32x4 dacc[4][2];          // v = x + delta + b2 of the previous tile
    float dmu = 0.f, drv = 0.f;
    float* dop = nullptr;      // out base of the previous tile (null = none)

    for (int t = blockIdx.x; t < NTILES; t += GRID) {
        const int b  = t >> 10;
        const int n0 = (t & 1023) << 6;
        const size_t rowbase = (size_t)b * NB;

        // no loop-top barrier: prev-iter xs/hs readers ordered by B4(ps2)

        // ---- stage: consume prefetched regs -> xs (bf16) ----
#pragma unroll
        for (int s = 0; s < 8; ++s) {
            const int q = tid + s * 256;
            const int r = q >> 5, c = q & 31;
            bf16x4 v4;
            v4[0] = (__bf16)xreg[s].x; v4[1] = (__bf16)xreg[s].y;
            v4[2] = (__bf16)xreg[s].z; v4[3] = (__bf16)xreg[s].w;
            *(bf16x4*)(xs + r * XS + c * 4) = v4;
        }
        if (tid < 64) {
            const int q = 2048 + tid;
            const int r = q >> 5, c = q & 31;
            bf16x4 v4;
            v4[0] = (__bf16)xhalo.x; v4[1] = (__bf16)xhalo.y;
            v4[2] = (__bf16)xhalo.z; v4[3] = (__bf16)xhalo.w;
            *(bf16x4*)(xs + r * XS + c * 4) = v4;
        }
        __syncthreads();  // B2: xs tile visible

        // ---- issue next tile's loads; they fly under GEMM1/GEMM2/LN ----
        if (t + GRID < NTILES) {
            const int tn  = t + GRID;
            const int bn  = tn >> 10;
            const int n0n = (tn & 1023) << 6;
            const size_t rbn = (size_t)bn * NB;
#pragma unroll
            for (int s = 0; s < 8; ++s) {
                const int q = tid + s * 256;
                const int r = q >> 5, c = q & 31;
                const int grow = (n0n - 1 + r + NB) & (NB - 1);
                xreg[s] = *(const float4*)(x + ((rbn + grow) * H + c * 4));
            }
            if (tid < 64) {
                const int q = 2048 + tid;
                const int r = q >> 5, c = q & 31;
                const int grow = (n0n - 1 + r + NB) & (NB - 1);
                xhalo = *(const float4*)(x + ((rbn + grow) * H + c * 4));
            }
        }

        // ---- deferred normalize + relu + store for PREVIOUS tile ----
        // Pure reg/global/s_gamma work: scheduler interleaves it with GEMM1's
        // MFMA+ds_read shadow below (VALU and MFMA are separate pipes).
        if (dop) {
            const f32x4 gm0 = *(const f32x4*)(s_gamma + col0 + g * 4);
            const f32x4 gm1 = *(const f32x4*)(s_gamma + col0 + 16 + g * 4);
            const f32x4 bt0 = *(const f32x4*)(s_beta + col0 + g * 4);
            const f32x4 bt1 = *(const f32x4*)(s_beta + col0 + 16 + g * 4);
#pragma unroll
            for (int rt = 0; rt < 4; ++rt) {
                const float mur = __shfl(dmu, (lane & 15) + rt * 16);
                const float rvr = __shfl(drv, (lane & 15) + rt * 16);
                float* op = dop + (rt * 16 + l) * H + col0;
                f32x4 o0, o1;
#pragma unroll
                for (int i = 0; i < 4; ++i) {
                    o0[i] = fmaxf((dacc[rt][0][i] - mur) * rvr * gm0[i] + bt0[i], 0.f);
                    o1[i] = fmaxf((dacc[rt][1][i] - mur) * rvr * gm1[i] + bt1[i], 0.f);
                }
                *(f32x4*)(op + g * 4)      = o0;
                *(f32x4*)(op + 16 + g * 4) = o1;
            }
        }

        // ---- GEMM1 (swapped): acc[rt][ct] = D[hcol quad][tilerow] ----
        f32x4 acc[4][2];
#pragma unroll
        for (int rt = 0; rt < 4; ++rt)
#pragma unroll
            for (int ct = 0; ct < 2; ++ct)
                acc[rt][ct] = (f32x4){0.f, 0.f, 0.f, 0.f};

        __builtin_amdgcn_s_setprio(1);
#pragma unroll
        for (int ks = 0; ks < 12; ++ks) {
            const int k  = ks * 32 + g * 8;          // k in [0,384)
            const int ro = k >> 7, kc = k & 127;
#pragma unroll
            for (int rt = 0; rt < 4; ++rt) {
                const bf16x8 a = *(const bf16x8*)(xs + (rt * 16 + l + ro) * XS + kc);
                acc[rt][0] = __builtin_amdgcn_mfma_f32_16x16x32_bf16(w1f[ks][0], a, acc[rt][0], 0, 0, 0);
                acc[rt][1] = __builtin_amdgcn_mfma_f32_16x16x32_bf16(w1f[ks][1], a, acc[rt][1], 0, 0, 0);
            }
        }
        __builtin_amdgcn_s_setprio(0);

        // relu + bias -> hs: lane holds cols col0+ct*16+g*4..+3 of row rt*16+l
        {
            const f32x4 b1q0 = *(const f32x4*)(s_b1 + col0 + g * 4);
            const f32x4 b1q1 = *(const f32x4*)(s_b1 + col0 + 16 + g * 4);
#pragma unroll
            for (int rt = 0; rt < 4; ++rt) {
                bf16x4 h0, h1;
#pragma unroll
                for (int i = 0; i < 4; ++i) {
                    h0[i] = (__bf16)fmaxf(acc[rt][0][i] + b1q0[i], 0.f);
                    h1[i] = (__bf16)fmaxf(acc[rt][1][i] + b1q1[i], 0.f);
                }
                *(bf16x4*)(hs + (rt * 16 + l) * HSS + col0 + g * 4)      = h0;
                *(bf16x4*)(hs + (rt * 16 + l) * HSS + col0 + 16 + g * 4) = h1;
            }
        }
        __syncthreads();  // B3: hs tile visible

        // ---- GEMM2 (swapped): delta[outcol quad][tilerow] -> dacc ----
#pragma unroll
        for (int rt = 0; rt < 4; ++rt)
#pragma unroll
            for (int ct = 0; ct < 2; ++ct)
                dacc[rt][ct] = (f32x4){0.f, 0.f, 0.f, 0.f};

        __builtin_amdgcn_s_setprio(1);
#pragma unroll
        for (int ks = 0; ks < 4; ++ks) {
            const bf16x8 wf0 = *(const bf16x8*)(w2w + ks * 1024 + lane * 8);
            const bf16x8 wf1 = *(const bf16x8*)(w2w + ks * 1024 + 512 + lane * 8);
#pragma unroll
            for (int rt = 0; rt < 4; ++rt) {
                const bf16x8 a = *(const bf16x8*)(hs + (rt * 16 + l) * HSS + ks * 32 + g * 8);
                dacc[rt][0] = __builtin_amdgcn_mfma_f32_16x16x32_bf16(wf0, a, dacc[rt][0], 0, 0, 0);
                dacc[rt][1] = __builtin_amdgcn_mfma_f32_16x16x32_bf16(wf1, a, dacc[rt][1], 0, 0, 0);
            }
        }
        __builtin_amdgcn_s_setprio(0);

        // ---- residual: v = x + delta + b2 (vectorized b64 x re-read) ----
        {
            const f32x4 b2q0 = *(const f32x4*)(s_b2 + col0 + g * 4);
            const f32x4 b2q1 = *(const f32x4*)(s_b2 + col0 + 16 + g * 4);
#pragma unroll
            for (int rt = 0; rt < 4; ++rt) {
                const bf16x4 xv0 = *(const bf16x4*)(xs + (rt * 16 + l + 1) * XS + col0 + g * 4);
                const bf16x4 xv1 = *(const bf16x4*)(xs + (rt * 16 + l + 1) * XS + col0 + 16 + g * 4);
#pragma unroll
                for (int i = 0; i < 4; ++i) {
                    dacc[rt][0][i] += b2q0[i] + (float)xv0[i];
                    dacc[rt][1][i] += b2q1[i] + (float)xv1[i];
                }
            }
        }

        // ---- LN partials: per-lane (s, sum v^2) over its 8 cols, per rt ----
#pragma unroll
        for (int rt = 0; rt < 4; ++rt) {
            float s = 0.f, qq = 0.f;
#pragma unroll
            for (int ct = 0; ct < 2; ++ct)
#pragma unroll
                for (int i = 0; i < 4; ++i) {
                    const float v = dacc[rt][ct][i];
                    s += v; qq += v * v;
                }
            ps2[(rt * 16 + l) * PSS + wid * 4 + g] = make_float2(s, qq);
        }
        __syncthreads();  // B4: partials visible; frees xs/hs for next iter

        // ---- cheap stats now; heavy normalize deferred to next iteration ----
        {
            const f32x4* pp = (const f32x4*)(ps2 + lane * PSS);  // 144B rows
            float S = 0.f, Q = 0.f;
#pragma unroll
            for (int j = 0; j < 4; ++j) {
                const f32x4 e0 = pp[2 * j];
                const f32x4 e1 = pp[2 * j + 1];
                S += (e0[0] + e0[2]) + (e1[0] + e1[2]);
                Q += (e0[1] + e0[3]) + (e1[1] + e1[3]);
            }
            dmu = S * (1.f / 128.f);
            const float var = Q * (1.f / 128.f) - dmu * dmu;
            drv = rsqrtf(var + 1e-5f);
            dop = out + (rowbase + n0) * H;
        }
    }

    // ---- pipeline drain: last tile's normalize + store ----
    if (dop) {
        const f32x4 gm0 = *(const f32x4*)(s_gamma + col0 + g * 4);
        const f32x4 gm1 = *(const f32x4*)(s_gamma + col0 + 16 + g * 4);
        const f32x4 bt0 = *(const f32x4*)(s_beta + col0 + g * 4);
        const f32x4 bt1 = *(const f32x4*)(s_beta + col0 + 16 + g * 4);
#pragma unroll
        for (int rt = 0; rt < 4; ++rt) {
            const float mur = __shfl(dmu, (lane & 15) + rt * 16);
            const float rvr = __shfl(drv, (lane & 15) + rt * 16);
            float* op = dop + (rt * 16 + l) * H + col0;
            f32x4 o0, o1;
#pragma unroll
            for (int i = 0; i < 4; ++i) {
                o0[i] = fmaxf((dacc[rt][0][i] - mur) * rvr * gm0[i] + bt0[i], 0.f);
                o1[i] = fmaxf((dacc[rt][1][i] - mur) * rvr * gm1[i] + bt1[i], 0.f);
            }
            *(f32x4*)(op + g * 4)      = o0;
            *(f32x4*)(op + 16 + g * 4) = o1;
        }
    }
}

extern "C" void kernel_launch(void* const* d_in, const int* in_sizes, int n_in,
                              void* d_out, int out_size, void* d_ws, size_t ws_size,
                              hipStream_t stream) {
    const float* x     = (const float*)d_in[0];
    const float* W1    = (const float*)d_in[1];
    const float* b1    = (const float*)d_in[2];
    const float* W2    = (const float*)d_in[3];
    const float* b2    = (const float*)d_in[4];
    const float* gamma = (const float*)d_in[5];
    const float* beta  = (const float*)d_in[6];
    float* out = (float*)d_out;

    // 512 blocks = 2 resident blocks/CU * 256 CUs; grid-stride over 4096 tiles
    cbb_kernel<<<GRID, 256, 0, stream>>>(x, W1, b1, W2, b2, gamma, beta, out);
}

// Round 11
// 264.379 us; speedup vs baseline: 1.5348x; 1.0203x over previous
//
#include <hip/hip_runtime.h>

// Fused CircularBoundaryBlock:
//   out = relu(LN(x + W2 @ relu(W1 @ [roll(x,1), x, roll(x,-1)] + b1) + b2))
// B=4, N=65536, H=128, fp32 I/O, bf16 MFMA internally.
//
// v12 = v8 + counted barriers (T4). Single-variable experiment.
//   hipcc emits `s_waitcnt vmcnt(0) lgkmcnt(0)` before every __syncthreads()
//   barrier — draining the 9 T14 prefetch loads (issued after B2) and the 8
//   output stores at B3/B4, every iteration. That amputates the prefetch
//   pipeline one barrier after issue and serializes on HBM store-ack at each
//   phase boundary; with all pipes <25% busy and 8 waves/CU (register-band
//   cap, settled by v2/v4/v9/v10), this drain is the prime stall suspect.
//   Intra-kernel correctness only ever publishes LDS state across barriers
//   (no thread reads another thread's global writes), so:
//     __syncthreads()  ->  { s_waitcnt lgkmcnt(0); raw s_barrier }
//   (HipKittens pattern, s05 techniques (1)+(2)). Global loads/stores stay
//   in flight across barriers; the compiler emits a counted vmcnt before
//   xreg's actual use at the next stage.
// Everything else byte-identical to v8 (best, 98us/dispatch): W1 frags in
// regs, W2 frags in LDS, swapped-operand MFMA, LN-direct epilogue (no vs),
// biases/gamma/beta in tiny LDS, T14 stage split + halo prefetch, 3
// barriers/iter, setprio, 256 thr, 512 blocks, 2 blocks/CU.

typedef __bf16 bf16x8 __attribute__((ext_vector_type(8)));
typedef __bf16 bf16x4 __attribute__((ext_vector_type(4)));
typedef float  f32x4  __attribute__((ext_vector_type(4)));

#define H      128
#define NB     65536        // rows per batch
#define TILE   64
#define XS     136          // x LDS stride (bf16 elems)
#define HSS    136          // h LDS stride (bf16 elems)
#define PSS    18           // ps2 stride (float2), 144 B: 16B-aligned rows
#define NTILES 4096         // 4 * 65536 / 64
#define GRID   512          // 2 blocks/CU * 256 CUs

// LDS-only barrier: publish ds_writes, do NOT drain global loads/stores.
#define LDS_BAR() do {                                        \
    asm volatile("s_waitcnt lgkmcnt(0)" ::: "memory");        \
    __builtin_amdgcn_s_barrier();                             \
} while (0)

__global__ __launch_bounds__(256, 2)
void cbb_kernel(const float* __restrict__ x, const float* __restrict__ W1,
                const float* __restrict__ b1, const float* __restrict__ W2,
                const float* __restrict__ b2, const float* __restrict__ gamma,
                const float* __restrict__ beta, float* __restrict__ out) {
    // xs (66*136 bf16) + hs (64*136 bf16) = 35360 B (no vs buffer)
    __shared__ __align__(16) char raw[(66 * XS + 64 * HSS) * 2];
    __bf16* xs = (__bf16*)raw;
    __bf16* hs = xs + 66 * XS;
    __shared__ __align__(16) __bf16 w2s[16384];    // W2 frags, 32 KB, persistent
    __shared__ __align__(16) float2 ps2[64 * PSS]; // LN partials, 9216 B
    __shared__ __align__(16) float s_b1[128], s_b2[128], s_gamma[128], s_beta[128];

    const int tid  = threadIdx.x;
    const int wid  = tid >> 6;
    const int lane = tid & 63;
    const int l    = lane & 15;   // MFMA n index (tile row, after swap)
    const int g    = lane >> 4;   // MFMA quad
    const int col0 = wid * 32;

    if (tid < 128) {
        s_b1[tid] = b1[tid];   s_b2[tid]   = b2[tid];
        s_gamma[tid] = gamma[tid]; s_beta[tid] = beta[tid];
    }

    // ---- W1 B-fragments persistent in registers (this wave's 32-col slice) ----
    bf16x8 w1f[12][2];
#pragma unroll
    for (int ks = 0; ks < 12; ++ks) {
#pragma unroll
        for (int ct = 0; ct < 2; ++ct) {
            const int cc = col0 + ct * 16 + l;
            bf16x8 f;
#pragma unroll
            for (int j = 0; j < 8; ++j)
                f[j] = (__bf16)W1[(ks * 32 + g * 8 + j) * H + cc];
            w1f[ks][ct] = f;
        }
    }

    // ---- W2 B-fragments -> LDS, fragment-ordered (once per block) ----
    // layout: w2s[w*4096 + ks*1024 + ct*512 + lane*8 + j]
    for (int idx = tid; idx < 16384; idx += 256) {
        const int j  = idx & 7;
        const int ln = (idx >> 3) & 63;
        const int ct = (idx >> 9) & 1;
        const int ks = (idx >> 10) & 3;
        const int w  = idx >> 12;
        const int row = ks * 32 + (ln >> 4) * 8 + j;
        const int col = w * 32 + ct * 16 + (ln & 15);
        w2s[idx] = (__bf16)W2[row * H + col];
    }
    const __bf16* w2w = w2s + wid * 4096;

    // ---- T14 prefetch: full 66-row halo tile (8 float4 + tid<64 halo) ----
    float4 xreg[8];
    float4 xhalo;
    {
        const int t  = blockIdx.x;
        const int b  = t >> 10;
        const int n0 = (t & 1023) << 6;
        const size_t rowbase = (size_t)b * NB;
#pragma unroll
        for (int s = 0; s < 8; ++s) {
            const int q = tid + s * 256;            // q < 2048 -> rows 0..63
            const int r = q >> 5, c = q & 31;
            const int grow = (n0 - 1 + r + NB) & (NB - 1);
            xreg[s] = *(const float4*)(x + ((rowbase + grow) * H + c * 4));
        }
        if (tid < 64) {                              // rows 64,65
            const int q = 2048 + tid;
            const int r = q >> 5, c = q & 31;
            const int grow = (n0 - 1 + r + NB) & (NB - 1);
            xhalo = *(const float4*)(x + ((rowbase + grow) * H + c * 4));
        }
    }

    for (int t = blockIdx.x; t < NTILES; t += GRID) {
        const int b  = t >> 10;
        const int n0 = (t & 1023) << 6;
        const size_t rowbase = (size_t)b * NB;

        // no loop-top barrier: prev-iter xs/hs readers ordered by B4(ps2)

        // ---- stage: consume prefetched regs -> xs (bf16) ----
#pragma unroll
        for (int s = 0; s < 8; ++s) {
            const int q = tid + s * 256;
            const int r = q >> 5, c = q & 31;
            bf16x4 v4;
            v4[0] = (__bf16)xreg[s].x; v4[1] = (__bf16)xreg[s].y;
            v4[2] = (__bf16)xreg[s].z; v4[3] = (__bf16)xreg[s].w;
            *(bf16x4*)(xs + r * XS + c * 4) = v4;
        }
        if (tid < 64) {
            const int q = 2048 + tid;
            const int r = q >> 5, c = q & 31;
            bf16x4 v4;
            v4[0] = (__bf16)xhalo.x; v4[1] = (__bf16)xhalo.y;
            v4[2] = (__bf16)xhalo.z; v4[3] = (__bf16)xhalo.w;
            *(bf16x4*)(xs + r * XS + c * 4) = v4;
        }
        LDS_BAR();  // B2: xs tile visible (LDS only; globals stay in flight)

        // ---- issue next tile's loads; they fly under GEMM1/GEMM2/LN ----
        if (t + GRID < NTILES) {
            const int tn  = t + GRID;
            const int bn  = tn >> 10;
            const int n0n = (tn & 1023) << 6;
            const size_t rbn = (size_t)bn * NB;
#pragma unroll
            for (int s = 0; s < 8; ++s) {
                const int q = tid + s * 256;
                const int r = q >> 5, c = q & 31;
                const int grow = (n0n - 1 + r + NB) & (NB - 1);
                xreg[s] = *(const float4*)(x + ((rbn + grow) * H + c * 4));
            }
            if (tid < 64) {
                const int q = 2048 + tid;
                const int r = q >> 5, c = q & 31;
                const int grow = (n0n - 1 + r + NB) & (NB - 1);
                xhalo = *(const float4*)(x + ((rbn + grow) * H + c * 4));
            }
        }

        // ---- GEMM1 (swapped): acc[rt][ct] = D[hcol quad][tilerow] ----
        f32x4 acc[4][2];
#pragma unroll
        for (int rt = 0; rt < 4; ++rt)
#pragma unroll
            for (int ct = 0; ct < 2; ++ct)
                acc[rt][ct] = (f32x4){0.f, 0.f, 0.f, 0.f};

        __builtin_amdgcn_s_setprio(1);
#pragma unroll
        for (int ks = 0; ks < 12; ++ks) {
            const int k  = ks * 32 + g * 8;          // k in [0,384)
            const int ro = k >> 7, kc = k & 127;
#pragma unroll
            for (int rt = 0; rt < 4; ++rt) {
                const bf16x8 a = *(const bf16x8*)(xs + (rt * 16 + l + ro) * XS + kc);
                acc[rt][0] = __builtin_amdgcn_mfma_f32_16x16x32_bf16(w1f[ks][0], a, acc[rt][0], 0, 0, 0);
                acc[rt][1] = __builtin_amdgcn_mfma_f32_16x16x32_bf16(w1f[ks][1], a, acc[rt][1], 0, 0, 0);
            }
        }
        __builtin_amdgcn_s_setprio(0);

        // relu + bias -> hs: lane holds cols col0+ct*16+g*4..+3 of row rt*16+l
        {
            const f32x4 b1q0 = *(const f32x4*)(s_b1 + col0 + g * 4);
            const f32x4 b1q1 = *(const f32x4*)(s_b1 + col0 + 16 + g * 4);
#pragma unroll
            for (int rt = 0; rt < 4; ++rt) {
                bf16x4 h0, h1;
#pragma unroll
                for (int i = 0; i < 4; ++i) {
                    h0[i] = (__bf16)fmaxf(acc[rt][0][i] + b1q0[i], 0.f);
                    h1[i] = (__bf16)fmaxf(acc[rt][1][i] + b1q1[i], 0.f);
                }
                *(bf16x4*)(hs + (rt * 16 + l) * HSS + col0 + g * 4)      = h0;
                *(bf16x4*)(hs + (rt * 16 + l) * HSS + col0 + 16 + g * 4) = h1;
            }
        }
        LDS_BAR();  // B3: hs tile visible (prefetch + stores NOT drained)

        // ---- GEMM2 (swapped): delta[outcol quad][tilerow] ----
        f32x4 acc2[4][2];
#pragma unroll
        for (int rt = 0; rt < 4; ++rt)
#pragma unroll
            for (int ct = 0; ct < 2; ++ct)
                acc2[rt][ct] = (f32x4){0.f, 0.f, 0.f, 0.f};

        __builtin_amdgcn_s_setprio(1);
#pragma unroll
        for (int ks = 0; ks < 4; ++ks) {
            const bf16x8 wf0 = *(const bf16x8*)(w2w + ks * 1024 + lane * 8);
            const bf16x8 wf1 = *(const bf16x8*)(w2w + ks * 1024 + 512 + lane * 8);
#pragma unroll
            for (int rt = 0; rt < 4; ++rt) {
                const bf16x8 a = *(const bf16x8*)(hs + (rt * 16 + l) * HSS + ks * 32 + g * 8);
                acc2[rt][0] = __builtin_amdgcn_mfma_f32_16x16x32_bf16(wf0, a, acc2[rt][0], 0, 0, 0);
                acc2[rt][1] = __builtin_amdgcn_mfma_f32_16x16x32_bf16(wf1, a, acc2[rt][1], 0, 0, 0);
            }
        }
        __builtin_amdgcn_s_setprio(0);

        // ---- residual: v = x + delta + b2 (vectorized b64 x re-read) ----
        {
            const f32x4 b2q0 = *(const f32x4*)(s_b2 + col0 + g * 4);
            const f32x4 b2q1 = *(const f32x4*)(s_b2 + col0 + 16 + g * 4);
#pragma unroll
            for (int rt = 0; rt < 4; ++rt) {
                const bf16x4 xv0 = *(const bf16x4*)(xs + (rt * 16 + l + 1) * XS + col0 + g * 4);
                const bf16x4 xv1 = *(const bf16x4*)(xs + (rt * 16 + l + 1) * XS + col0 + 16 + g * 4);
#pragma unroll
                for (int i = 0; i < 4; ++i) {
                    acc2[rt][0][i] += b2q0[i] + (float)xv0[i];
                    acc2[rt][1][i] += b2q1[i] + (float)xv1[i];
                }
            }
        }

        // ---- LN partials: per-lane (s, sum v^2) over its 8 cols, per rt ----
#pragma unroll
        for (int rt = 0; rt < 4; ++rt) {
            float s = 0.f, qq = 0.f;
#pragma unroll
            for (int ct = 0; ct < 2; ++ct)
#pragma unroll
                for (int i = 0; i < 4; ++i) {
                    const float v = acc2[rt][ct][i];
                    s += v; qq += v * v;
                }
            ps2[(rt * 16 + l) * PSS + wid * 4 + g] = make_float2(s, qq);
        }
        LDS_BAR();  // B4: partials visible; frees xs/hs for next iter

        // ---- row stats for assigned row (= lane), chunked reads ----
        float mu, rv;
        {
            const f32x4* pp = (const f32x4*)(ps2 + lane * PSS);  // 144B rows
            float S = 0.f, Q = 0.f;
#pragma unroll
            for (int j = 0; j < 4; ++j) {
                const f32x4 e0 = pp[2 * j];
                const f32x4 e1 = pp[2 * j + 1];
                S += (e0[0] + e0[2]) + (e1[0] + e1[2]);
                Q += (e0[1] + e0[3]) + (e1[1] + e1[3]);
            }
            mu = S * (1.f / 128.f);
            const float var = Q * (1.f / 128.f) - mu * mu;
            rv = rsqrtf(var + 1e-5f);
        }

        // ---- normalize + relu in-reg, store f32x4 direct to global ----
        {
            const f32x4 gm0 = *(const f32x4*)(s_gamma + col0 + g * 4);
            const f32x4 gm1 = *(const f32x4*)(s_gamma + col0 + 16 + g * 4);
            const f32x4 bt0 = *(const f32x4*)(s_beta + col0 + g * 4);
            const f32x4 bt1 = *(const f32x4*)(s_beta + col0 + 16 + g * 4);
#pragma unroll
            for (int rt = 0; rt < 4; ++rt) {
                const float mur = __shfl(mu, (lane & 15) + rt * 16);
                const float rvr = __shfl(rv, (lane & 15) + rt * 16);
                float* op = out + (rowbase + n0 + rt * 16 + l) * H + col0;
                f32x4 o0, o1;
#pragma unroll
                for (int i = 0; i < 4; ++i) {
                    o0[i] = fmaxf((acc2[rt][0][i] - mur) * rvr * gm0[i] + bt0[i], 0.f);
                    o1[i] = fmaxf((acc2[rt][1][i] - mur) * rvr * gm1[i] + bt1[i], 0.f);
                }
                *(f32x4*)(op + g * 4)      = o0;
                *(f32x4*)(op + 16 + g * 4) = o1;
            }
        }
    }
}

extern "C" void kernel_launch(void* const* d_in, const int* in_sizes, int n_in,
                              void* d_out, int out_size, void* d_ws, size_t ws_size,
                              hipStream_t stream) {
    const float* x     = (const float*)d_in[0];
    const float* W1    = (const float*)d_in[1];
    const float* b1    = (const float*)d_in[2];
    const float* W2    = (const float*)d_in[3];
    const float* b2    = (const float*)d_in[4];
    const float* gamma = (const float*)d_in[5];
    const float* beta  = (const float*)d_in[6];
    float* out = (float*)d_out;

    // 512 blocks = 2 resident blocks/CU * 256 CUs; grid-stride over 4096 tiles
    cbb_kernel<<<GRID, 256, 0, stream>>>(x, W1, b1, W2, b2, gamma, beta, out);
}